// Round 1
// baseline (1810.890 us; speedup 1.0000x reference)
//
#include <hip/hip_runtime.h>

#define N_NODES 100000
#define E_EDGES 1600000
#define IN_CH   512
#define HID     256
#define OUT_CH  32
#define K_STEPS 10

typedef unsigned short u16;
typedef unsigned int   u32;

__device__ __forceinline__ float b2f(u16 u) {
    union { u32 i; float f; } x; x.i = ((u32)u) << 16; return x.f;
}
__device__ __forceinline__ u16 f2b(float f) {
    union { float f; u32 u; } x; x.f = f;
    u32 r = x.u + 0x7fffu + ((x.u >> 16) & 1u);
    return (u16)(r >> 16);
}

// ---------------- preprocessing: degree, dinv, scan, CSR fill ----------------

__global__ __launch_bounds__(256) void k_count(const int* __restrict__ col, int* __restrict__ cnt) {
    int i = blockIdx.x * 256 + threadIdx.x;
    if (i < E_EDGES) atomicAdd(&cnt[col[i]], 1);
}

__global__ __launch_bounds__(256) void k_dinv(const int* __restrict__ cnt, float* __restrict__ dinv) {
    int i = blockIdx.x * 256 + threadIdx.x;
    if (i < N_NODES) dinv[i] = rsqrtf((float)(cnt[i] + 1));  // +1 self-loop
}

__global__ __launch_bounds__(256) void k_blocksum(const int* __restrict__ cnt, int* __restrict__ bs) {
    int b = blockIdx.x, t = threadIdx.x;
    int idx = b * 1024 + t * 4;
    int s = 0;
    #pragma unroll
    for (int j = 0; j < 4; ++j) if (idx + j < N_NODES) s += cnt[idx + j];
    #pragma unroll
    for (int d = 32; d > 0; d >>= 1) s += __shfl_down(s, d, 64);
    __shared__ int smem[4];
    int lane = t & 63, w = t >> 6;
    if (lane == 0) smem[w] = s;
    __syncthreads();
    if (t == 0) bs[b] = smem[0] + smem[1] + smem[2] + smem[3];
}

__global__ void k_scanblocks(const int* __restrict__ bs, int* __restrict__ bo, int nb) {
    int t = threadIdx.x;  // 128 threads, nb <= 128
    int v = (t < nb) ? bs[t] : 0;
    int incl = v;
    int lane = t & 63, w = t >> 6;
    #pragma unroll
    for (int d = 1; d < 64; d <<= 1) { int tt = __shfl_up(incl, d, 64); if (lane >= d) incl += tt; }
    __shared__ int wsum[2];
    if (lane == 63) wsum[w] = incl;
    __syncthreads();
    int add = (w == 1) ? wsum[0] : 0;
    if (t < nb) bo[t] = add + incl - v;  // exclusive
}

__global__ __launch_bounds__(256) void k_scanwithin(const int* __restrict__ cnt, const int* __restrict__ bo,
                                                    int* __restrict__ off) {
    int b = blockIdx.x, t = threadIdx.x;
    int idx = b * 1024 + t * 4;
    int v[4]; int s = 0;
    #pragma unroll
    for (int j = 0; j < 4; ++j) { v[j] = (idx + j < N_NODES) ? cnt[idx + j] : 0; s += v[j]; }
    int incl = s;
    int lane = t & 63, w = t >> 6;
    #pragma unroll
    for (int d = 1; d < 64; d <<= 1) { int tt = __shfl_up(incl, d, 64); if (lane >= d) incl += tt; }
    __shared__ int wsum[4];
    if (lane == 63) wsum[w] = incl;
    __syncthreads();
    int woff = 0;
    #pragma unroll
    for (int k = 0; k < 4; ++k) if (k < w) woff += wsum[k];
    int run = bo[b] + woff + incl - s;  // exclusive prefix for first element
    #pragma unroll
    for (int j = 0; j < 4; ++j) { if (idx + j < N_NODES) off[idx + j] = run; run += v[j]; }
    if (b == 0 && t == 0) off[N_NODES] = E_EDGES;
}

__global__ __launch_bounds__(256) void k_fill(const int* __restrict__ row, const int* __restrict__ col,
                                              const float* __restrict__ dinv, const int* __restrict__ off,
                                              int* __restrict__ cursor, int* __restrict__ csr_row,
                                              float* __restrict__ csr_w) {
    int i = blockIdx.x * 256 + threadIdx.x;
    if (i < E_EDGES) {
        int c = col[i], r = row[i];
        int pos = off[c] + atomicAdd(&cursor[c], 1);
        csr_row[pos] = r;
        csr_w[pos]   = dinv[r] * dinv[c];
    }
}

// ---------------- GEMMs (fp32 vector-ALU, 128x128 tile, 8x8 micro) ----------------
// Out[m][n] = act(A[m][:] . Wt[n][:] + bias[n]) ; Wt is row-major [Ncols][KDIM] (i.e. B^T)

template<int KDIM, bool ABF16, bool RESID>
__global__ __launch_bounds__(256) void gemm_big(const float* __restrict__ Af, const u16* __restrict__ Ab,
                                                const float* __restrict__ Wt, const float* __restrict__ bias,
                                                const u16* __restrict__ resid, u16* __restrict__ Out, int M) {
    constexpr int BM = 128, BN = 128, BK = 16;
    __shared__ float As[BK][BM + 4];
    __shared__ float Bs[BK][BN + 4];
    int t = threadIdx.x;
    int row0 = blockIdx.x * BM;
    int col0 = blockIdx.y * BN;

    float acc[8][8];
    #pragma unroll
    for (int i = 0; i < 8; ++i)
        #pragma unroll
        for (int j = 0; j < 8; ++j) acc[i][j] = 0.f;

    for (int k0 = 0; k0 < KDIM; k0 += BK) {
        // stage A: 128 rows x 16 k
        #pragma unroll
        for (int rep = 0; rep < 2; ++rep) {
            int idx = rep * 256 + t;
            int r = idx >> 2, ch = idx & 3;
            int gr = row0 + r;
            float v0, v1, v2, v3;
            if (gr < M) {
                if constexpr (ABF16) {
                    ushort4 u = *(const ushort4*)&Ab[(size_t)gr * KDIM + k0 + ch * 4];
                    v0 = b2f(u.x); v1 = b2f(u.y); v2 = b2f(u.z); v3 = b2f(u.w);
                } else {
                    float4 f = *(const float4*)&Af[(size_t)gr * KDIM + k0 + ch * 4];
                    v0 = f.x; v1 = f.y; v2 = f.z; v3 = f.w;
                }
            } else { v0 = v1 = v2 = v3 = 0.f; }
            As[ch * 4 + 0][r] = v0; As[ch * 4 + 1][r] = v1;
            As[ch * 4 + 2][r] = v2; As[ch * 4 + 3][r] = v3;
        }
        // stage W (B^T): 128 cols x 16 k
        #pragma unroll
        for (int rep = 0; rep < 2; ++rep) {
            int idx = rep * 256 + t;
            int nn = idx >> 2, ch = idx & 3;
            float4 f = *(const float4*)&Wt[(size_t)(col0 + nn) * KDIM + k0 + ch * 4];
            Bs[ch * 4 + 0][nn] = f.x; Bs[ch * 4 + 1][nn] = f.y;
            Bs[ch * 4 + 2][nn] = f.z; Bs[ch * 4 + 3][nn] = f.w;
        }
        __syncthreads();
        int ty = t >> 4, tx = t & 15;
        #pragma unroll
        for (int kk = 0; kk < BK; ++kk) {
            float a[8], w[8];
            *(float4*)&a[0] = *(const float4*)&As[kk][ty * 8];
            *(float4*)&a[4] = *(const float4*)&As[kk][ty * 8 + 4];
            *(float4*)&w[0] = *(const float4*)&Bs[kk][tx * 8];
            *(float4*)&w[4] = *(const float4*)&Bs[kk][tx * 8 + 4];
            #pragma unroll
            for (int i = 0; i < 8; ++i)
                #pragma unroll
                for (int j = 0; j < 8; ++j) acc[i][j] = fmaf(a[i], w[j], acc[i][j]);
        }
        __syncthreads();
    }

    int ty = t >> 4, tx = t & 15;
    float bcol[8];
    #pragma unroll
    for (int j = 0; j < 8; ++j) bcol[j] = bias[col0 + tx * 8 + j];
    #pragma unroll
    for (int i = 0; i < 8; ++i) {
        int gr = row0 + ty * 8 + i;
        if (gr < M) {
            union { u16 pk[8]; uint4 v; } P;
            #pragma unroll
            for (int j = 0; j < 8; ++j) {
                float v = fmaxf(acc[i][j] + bcol[j], 0.f);
                if constexpr (RESID) {
                    v = b2f(resid[(size_t)gr * HID + col0 + tx * 8 + j]) + v;
                }
                P.pk[j] = f2b(v);
            }
            *(uint4*)&Out[(size_t)gr * HID + col0 + tx * 8] = P.v;
        }
    }
}

// GEMM3: h0[m][c] = xres[m][:] . W2[c][:] + b2[c], 128x32 tile, 4x4 micro
__global__ __launch_bounds__(256) void gemm_out(const u16* __restrict__ xres, const float* __restrict__ W2,
                                                const float* __restrict__ b2, float* __restrict__ h0, int M) {
    constexpr int BM = 128, BK = 16, KDIM = HID;
    __shared__ float As[BK][BM + 4];
    __shared__ float Bs[BK][OUT_CH + 4];
    int t = threadIdx.x;
    int row0 = blockIdx.x * BM;

    float acc[4][4];
    #pragma unroll
    for (int i = 0; i < 4; ++i)
        #pragma unroll
        for (int j = 0; j < 4; ++j) acc[i][j] = 0.f;

    for (int k0 = 0; k0 < KDIM; k0 += BK) {
        #pragma unroll
        for (int rep = 0; rep < 2; ++rep) {
            int idx = rep * 256 + t;
            int r = idx >> 2, ch = idx & 3;
            int gr = row0 + r;
            float v0, v1, v2, v3;
            if (gr < M) {
                ushort4 u = *(const ushort4*)&xres[(size_t)gr * KDIM + k0 + ch * 4];
                v0 = b2f(u.x); v1 = b2f(u.y); v2 = b2f(u.z); v3 = b2f(u.w);
            } else { v0 = v1 = v2 = v3 = 0.f; }
            As[ch * 4 + 0][r] = v0; As[ch * 4 + 1][r] = v1;
            As[ch * 4 + 2][r] = v2; As[ch * 4 + 3][r] = v3;
        }
        if (t < 128) {
            int nn = t >> 2, ch = t & 3;
            float4 f = *(const float4*)&W2[(size_t)nn * KDIM + k0 + ch * 4];
            Bs[ch * 4 + 0][nn] = f.x; Bs[ch * 4 + 1][nn] = f.y;
            Bs[ch * 4 + 2][nn] = f.z; Bs[ch * 4 + 3][nn] = f.w;
        }
        __syncthreads();
        int ty = t >> 3, tx = t & 7;  // rows ty*4, cols tx*4
        #pragma unroll
        for (int kk = 0; kk < BK; ++kk) {
            float a[4], w[4];
            *(float4*)&a[0] = *(const float4*)&As[kk][ty * 4];
            *(float4*)&w[0] = *(const float4*)&Bs[kk][tx * 4];
            #pragma unroll
            for (int i = 0; i < 4; ++i)
                #pragma unroll
                for (int j = 0; j < 4; ++j) acc[i][j] = fmaf(a[i], w[j], acc[i][j]);
        }
        __syncthreads();
    }
    int ty = t >> 3, tx = t & 7;
    #pragma unroll
    for (int i = 0; i < 4; ++i) {
        int gr = row0 + ty * 4 + i;
        if (gr < M) {
            float4 v;
            v.x = acc[i][0] + b2[tx * 4 + 0];
            v.y = acc[i][1] + b2[tx * 4 + 1];
            v.z = acc[i][2] + b2[tx * 4 + 2];
            v.w = acc[i][3] + b2[tx * 4 + 3];
            *(float4*)&h0[(size_t)gr * OUT_CH + tx * 4] = v;
        }
    }
}

// ---------------- propagation: one wave per node, CSR gather ----------------

__global__ __launch_bounds__(256) void k_prop(const float* __restrict__ hin, float* __restrict__ hout,
                                              const float* __restrict__ h0, const int* __restrict__ off,
                                              const int* __restrict__ csr_row, const float* __restrict__ csr_w,
                                              const float* __restrict__ dinv) {
    int gw = (blockIdx.x * 256 + threadIdx.x) >> 6;
    if (gw >= N_NODES) return;
    int lane = threadIdx.x & 63;
    int c = lane & 31;
    int half = lane >> 5;
    int s = off[gw], e = off[gw + 1];
    float acc = 0.f;
    for (int j = s + half; j < e; j += 2) {
        int r = csr_row[j];
        float wv = csr_w[j];
        acc = fmaf(wv, hin[(size_t)r * OUT_CH + c], acc);
    }
    acc += __shfl_xor(acc, 32, 64);
    if (half == 0) {
        float dv = dinv[gw];
        float agg = acc + dv * dv * hin[(size_t)gw * OUT_CH + c];
        hout[(size_t)gw * OUT_CH + c] = 0.9f * agg + 0.1f * h0[(size_t)gw * OUT_CH + c];
    }
}

// ---------------- launch ----------------

extern "C" void kernel_launch(void* const* d_in, const int* in_sizes, int n_in,
                              void* d_out, int out_size, void* d_ws, size_t ws_size,
                              hipStream_t stream) {
    const float* x  = (const float*)d_in[0];
    const int*   ei = (const int*)d_in[1];      // [2][E]
    const float* W1 = (const float*)d_in[2];
    const float* b1 = (const float*)d_in[3];
    const float* Wr = (const float*)d_in[4];
    const float* br = (const float*)d_in[5];
    const float* W2 = (const float*)d_in[6];
    const float* b2 = (const float*)d_in[7];
    float* out = (float*)d_out;

    char* ws = (char*)d_ws;
    size_t pos = 0;
    auto alloc = [&](size_t bytes) {
        void* p = ws + pos;
        pos += (bytes + 255) & ~(size_t)255;
        return p;
    };
    u16*   h1      = (u16*)  alloc((size_t)N_NODES * HID * 2);
    u16*   xres    = (u16*)  alloc((size_t)N_NODES * HID * 2);
    float* h0      = (float*)alloc((size_t)N_NODES * OUT_CH * 4);
    float* bufA    = (float*)alloc((size_t)N_NODES * OUT_CH * 4);
    float* bufB    = (float*)alloc((size_t)N_NODES * OUT_CH * 4);
    float* dinv    = (float*)alloc((size_t)N_NODES * 4);
    int*   cnt     = (int*)  alloc((size_t)N_NODES * 4);
    int*   offs    = (int*)  alloc((size_t)(N_NODES + 1) * 4);
    int*   cursor  = (int*)  alloc((size_t)N_NODES * 4);
    int*   bs      = (int*)  alloc(1024);
    int*   bo      = (int*)  alloc(1024);
    int*   csr_row = (int*)  alloc((size_t)E_EDGES * 4);
    float* csr_w   = (float*)alloc((size_t)E_EDGES * 4);

    const int* e_row = ei;
    const int* e_col = ei + E_EDGES;

    hipMemsetAsync(cnt, 0, (size_t)N_NODES * 4, stream);
    hipMemsetAsync(cursor, 0, (size_t)N_NODES * 4, stream);

    const int NB = (N_NODES + 1023) / 1024;  // 98
    k_count<<<(E_EDGES + 255) / 256, 256, 0, stream>>>(e_col, cnt);
    k_dinv<<<(N_NODES + 255) / 256, 256, 0, stream>>>(cnt, dinv);
    k_blocksum<<<NB, 256, 0, stream>>>(cnt, bs);
    k_scanblocks<<<1, 128, 0, stream>>>(bs, bo, NB);
    k_scanwithin<<<NB, 256, 0, stream>>>(cnt, bo, offs);
    k_fill<<<(E_EDGES + 255) / 256, 256, 0, stream>>>(e_row, e_col, dinv, offs, cursor, csr_row, csr_w);

    dim3 g12((N_NODES + 127) / 128, HID / 128);
    gemm_big<IN_CH, false, false><<<g12, 256, 0, stream>>>(x, nullptr, W1, b1, nullptr, h1, N_NODES);
    gemm_big<HID, true, true><<<g12, 256, 0, stream>>>(nullptr, h1, Wr, br, h1, xres, N_NODES);
    gemm_out<<<(N_NODES + 127) / 128, 256, 0, stream>>>(xres, W2, b2, h0, N_NODES);

    const float* pin = h0;
    for (int s = 0; s < K_STEPS; ++s) {
        float* pout = (s == K_STEPS - 1) ? out : ((s & 1) ? bufB : bufA);
        k_prop<<<(N_NODES * 64 + 255) / 256, 256, 0, stream>>>(pin, pout, h0, offs, csr_row, csr_w, dinv);
        pin = pout;
    }
}

// Round 2
// 1196.764 us; speedup vs baseline: 1.5132x; 1.5132x over previous
//
#include <hip/hip_runtime.h>

#define N_NODES 100000
#define E_EDGES 1600000
#define IN_CH   512
#define HID     256
#define OUT_CH  32
#define K_STEPS 10

typedef unsigned short u16;
typedef unsigned int   u32;

typedef __attribute__((ext_vector_type(8))) short bf16x8;
typedef __attribute__((ext_vector_type(4))) float f32x4;

__device__ __forceinline__ float b2f(u16 u) {
    union { u32 i; float f; } x; x.i = ((u32)u) << 16; return x.f;
}
__device__ __forceinline__ u16 f2b(float f) {
    union { float f; u32 u; } x; x.f = f;
    u32 r = x.u + 0x7fffu + ((x.u >> 16) & 1u);
    return (u16)(r >> 16);
}

// async global->LDS, 16B per lane. LDS dest is wave-uniform base + lane*16.
__device__ __forceinline__ void load_lds16(const void* g, void* l) {
    __builtin_amdgcn_global_load_lds(
        (const __attribute__((address_space(1))) unsigned int*)g,
        (__attribute__((address_space(3))) unsigned int*)l,
        16, 0, 0);
}

// ---------------- casts ----------------

__global__ __launch_bounds__(256) void k_cast(const float* __restrict__ in, u16* __restrict__ out, int n4) {
    int i = blockIdx.x * 256 + threadIdx.x;
    if (i < n4) {
        float4 f = ((const float4*)in)[i];
        ushort4 u;
        u.x = f2b(f.x); u.y = f2b(f.y); u.z = f2b(f.z); u.w = f2b(f.w);
        ((ushort4*)out)[i] = u;
    }
}

// ---------------- preprocessing: degree, dinv, scan, CSR fill ----------------

__global__ __launch_bounds__(256) void k_count(const int* __restrict__ col, int* __restrict__ cnt) {
    int i = blockIdx.x * 256 + threadIdx.x;
    if (i < E_EDGES) atomicAdd(&cnt[col[i]], 1);
}

__global__ __launch_bounds__(256) void k_dinv(const int* __restrict__ cnt, float* __restrict__ dinv) {
    int i = blockIdx.x * 256 + threadIdx.x;
    if (i < N_NODES) dinv[i] = rsqrtf((float)(cnt[i] + 1));  // +1 self-loop
}

__global__ __launch_bounds__(256) void k_blocksum(const int* __restrict__ cnt, int* __restrict__ bs) {
    int b = blockIdx.x, t = threadIdx.x;
    int idx = b * 1024 + t * 4;
    int s = 0;
    #pragma unroll
    for (int j = 0; j < 4; ++j) if (idx + j < N_NODES) s += cnt[idx + j];
    #pragma unroll
    for (int d = 32; d > 0; d >>= 1) s += __shfl_down(s, d, 64);
    __shared__ int smem[4];
    int lane = t & 63, w = t >> 6;
    if (lane == 0) smem[w] = s;
    __syncthreads();
    if (t == 0) bs[b] = smem[0] + smem[1] + smem[2] + smem[3];
}

__global__ void k_scanblocks(const int* __restrict__ bs, int* __restrict__ bo, int nb) {
    int t = threadIdx.x;  // 128 threads, nb <= 128
    int v = (t < nb) ? bs[t] : 0;
    int incl = v;
    int lane = t & 63, w = t >> 6;
    #pragma unroll
    for (int d = 1; d < 64; d <<= 1) { int tt = __shfl_up(incl, d, 64); if (lane >= d) incl += tt; }
    __shared__ int wsum[2];
    if (lane == 63) wsum[w] = incl;
    __syncthreads();
    int add = (w == 1) ? wsum[0] : 0;
    if (t < nb) bo[t] = add + incl - v;  // exclusive
}

__global__ __launch_bounds__(256) void k_scanwithin(const int* __restrict__ cnt, const int* __restrict__ bo,
                                                    int* __restrict__ off) {
    int b = blockIdx.x, t = threadIdx.x;
    int idx = b * 1024 + t * 4;
    int v[4]; int s = 0;
    #pragma unroll
    for (int j = 0; j < 4; ++j) { v[j] = (idx + j < N_NODES) ? cnt[idx + j] : 0; s += v[j]; }
    int incl = s;
    int lane = t & 63, w = t >> 6;
    #pragma unroll
    for (int d = 1; d < 64; d <<= 1) { int tt = __shfl_up(incl, d, 64); if (lane >= d) incl += tt; }
    __shared__ int wsum[4];
    if (lane == 63) wsum[w] = incl;
    __syncthreads();
    int woff = 0;
    #pragma unroll
    for (int k = 0; k < 4; ++k) if (k < w) woff += wsum[k];
    int run = bo[b] + woff + incl - s;
    #pragma unroll
    for (int j = 0; j < 4; ++j) { if (idx + j < N_NODES) off[idx + j] = run; run += v[j]; }
    if (b == 0 && t == 0) off[N_NODES] = E_EDGES;
}

__global__ __launch_bounds__(256) void k_fill(const int* __restrict__ row, const int* __restrict__ col,
                                              const float* __restrict__ dinv, const int* __restrict__ off,
                                              int* __restrict__ cursor, int* __restrict__ csr_row,
                                              float* __restrict__ csr_w) {
    int i = blockIdx.x * 256 + threadIdx.x;
    if (i < E_EDGES) {
        int c = col[i], r = row[i];
        int pos = off[c] + atomicAdd(&cursor[c], 1);
        csr_row[pos] = r;
        csr_w[pos]   = dinv[r] * dinv[c];
    }
}

// ---------------- bf16 MFMA GEMM: 128x128 tile, 4 waves, 64x64/wave ----------------
// Out[m][n] = relu(A[m][:] . Bt[n][:] + bias[n]) (+ resid[m][n] if RESID), Out bf16 ld=256

template<int KDIM, bool RESID>
__global__ __launch_bounds__(256) void gemm_mfma(const u16* __restrict__ A,
                                                 const u16* __restrict__ Bt,
                                                 const float* __restrict__ bias,
                                                 const u16* __restrict__ resid,
                                                 u16* __restrict__ Out,
                                                 int M) {
    __shared__ u16 As[128 * 32];   // [row][k], 64B rows, no pad (global_load_lds layout)
    __shared__ u16 Bs[128 * 32];
    const int t = threadIdx.x;
    const int lane = t & 63, w = t >> 6;
    const int row0 = blockIdx.x * 128, col0 = blockIdx.y * 128;

    f32x4 acc[4][4] = {};

    const int rr = lane >> 2;   // row within 16-row chunk
    const int cc = lane & 3;    // 16B chunk within 64B row

    const int wr = (w >> 1) * 64, wc = (w & 1) * 64;
    const int fr = lane & 15, quad = lane >> 4;

    for (int k0 = 0; k0 < KDIM; k0 += 32) {
        #pragma unroll
        for (int rep = 0; rep < 2; ++rep) {
            int ii = w * 2 + rep;
            int gr = row0 + ii * 16 + rr;
            if (gr > M - 1) gr = M - 1;           // clamp: garbage rows never stored
            load_lds16(A + (size_t)gr * KDIM + k0 + cc * 8, &As[ii * 512]);
        }
        #pragma unroll
        for (int rep = 0; rep < 2; ++rep) {
            int ii = w * 2 + rep;
            int gc = col0 + ii * 16 + rr;         // always in-bounds (HID multiple of 128)
            load_lds16(Bt + (size_t)gc * KDIM + k0 + cc * 8, &Bs[ii * 512]);
        }
        __syncthreads();

        bf16x8 af[4], bfr[4];
        #pragma unroll
        for (int ti = 0; ti < 4; ++ti)
            af[ti] = *(const bf16x8*)&As[(wr + ti * 16 + fr) * 32 + quad * 8];
        #pragma unroll
        for (int tj = 0; tj < 4; ++tj)
            bfr[tj] = *(const bf16x8*)&Bs[(wc + tj * 16 + fr) * 32 + quad * 8];
        #pragma unroll
        for (int ti = 0; ti < 4; ++ti)
            #pragma unroll
            for (int tj = 0; tj < 4; ++tj)
                acc[ti][tj] = __builtin_amdgcn_mfma_f32_16x16x32_bf16(af[ti], bfr[tj], acc[ti][tj], 0, 0, 0);
        __syncthreads();
    }

    // epilogue: C/D layout col=lane&15, row=quad*4+reg
    #pragma unroll
    for (int tj = 0; tj < 4; ++tj) {
        int col = col0 + wc + tj * 16 + fr;
        float bv = bias[col];
        #pragma unroll
        for (int ti = 0; ti < 4; ++ti) {
            #pragma unroll
            for (int r = 0; r < 4; ++r) {
                int grow = row0 + wr + ti * 16 + quad * 4 + r;
                if (grow < M) {
                    float v = fmaxf(acc[ti][tj][r] + bv, 0.f);
                    if constexpr (RESID) v += b2f(resid[(size_t)grow * HID + col]);
                    Out[(size_t)grow * HID + col] = f2b(v);
                }
            }
        }
    }
}

// GEMM3: h0[m][c] = xres[m][:] . W2[c][:] + b2[c]  (VALU fp32, small)
__global__ __launch_bounds__(256) void gemm_out(const u16* __restrict__ xres, const float* __restrict__ W2,
                                                const float* __restrict__ b2, float* __restrict__ h0, int M) {
    constexpr int BM = 128, BK = 16, KDIM = HID;
    __shared__ float As[BK][BM + 4];
    __shared__ float Bs[BK][OUT_CH + 4];
    int t = threadIdx.x;
    int row0 = blockIdx.x * BM;

    float acc[4][4];
    #pragma unroll
    for (int i = 0; i < 4; ++i)
        #pragma unroll
        for (int j = 0; j < 4; ++j) acc[i][j] = 0.f;

    for (int k0 = 0; k0 < KDIM; k0 += BK) {
        #pragma unroll
        for (int rep = 0; rep < 2; ++rep) {
            int idx = rep * 256 + t;
            int r = idx >> 2, ch = idx & 3;
            int gr = row0 + r;
            float v0, v1, v2, v3;
            if (gr < M) {
                ushort4 u = *(const ushort4*)&xres[(size_t)gr * KDIM + k0 + ch * 4];
                v0 = b2f(u.x); v1 = b2f(u.y); v2 = b2f(u.z); v3 = b2f(u.w);
            } else { v0 = v1 = v2 = v3 = 0.f; }
            As[ch * 4 + 0][r] = v0; As[ch * 4 + 1][r] = v1;
            As[ch * 4 + 2][r] = v2; As[ch * 4 + 3][r] = v3;
        }
        if (t < 128) {
            int nn = t >> 2, ch = t & 3;
            float4 f = *(const float4*)&W2[(size_t)nn * KDIM + k0 + ch * 4];
            Bs[ch * 4 + 0][nn] = f.x; Bs[ch * 4 + 1][nn] = f.y;
            Bs[ch * 4 + 2][nn] = f.z; Bs[ch * 4 + 3][nn] = f.w;
        }
        __syncthreads();
        int ty = t >> 3, tx = t & 7;
        #pragma unroll
        for (int kk = 0; kk < BK; ++kk) {
            float a[4], wv[4];
            *(float4*)&a[0] = *(const float4*)&As[kk][ty * 4];
            *(float4*)&wv[0] = *(const float4*)&Bs[kk][tx * 4];
            #pragma unroll
            for (int i = 0; i < 4; ++i)
                #pragma unroll
                for (int j = 0; j < 4; ++j) acc[i][j] = fmaf(a[i], wv[j], acc[i][j]);
        }
        __syncthreads();
    }
    int ty = t >> 3, tx = t & 7;
    #pragma unroll
    for (int i = 0; i < 4; ++i) {
        int gr = row0 + ty * 4 + i;
        if (gr < M) {
            float4 v;
            v.x = acc[i][0] + b2[tx * 4 + 0];
            v.y = acc[i][1] + b2[tx * 4 + 1];
            v.z = acc[i][2] + b2[tx * 4 + 2];
            v.w = acc[i][3] + b2[tx * 4 + 3];
            *(float4*)&h0[(size_t)gr * OUT_CH + tx * 4] = v;
        }
    }
}

// ---------------- propagation: one wave per node, CSR gather, unroll x4 ----------------

__global__ __launch_bounds__(256) void k_prop(const float* __restrict__ hin, float* __restrict__ hout,
                                              const float* __restrict__ h0, const int* __restrict__ off,
                                              const int* __restrict__ csr_row, const float* __restrict__ csr_w,
                                              const float* __restrict__ dinv) {
    int gw = (blockIdx.x * 256 + threadIdx.x) >> 6;
    if (gw >= N_NODES) return;
    int lane = threadIdx.x & 63;
    int c = lane & 31;
    int half = lane >> 5;
    int s = off[gw], e = off[gw + 1];
    float acc = 0.f;
    int j = s + half;
    // 4 edges per half in flight (8 per wave)
    for (; j + 6 < e; j += 8) {
        int r0 = csr_row[j];     float w0 = csr_w[j];
        int r1 = csr_row[j + 2]; float w1 = csr_w[j + 2];
        int r2 = csr_row[j + 4]; float w2 = csr_w[j + 4];
        int r3 = csr_row[j + 6]; float w3 = csr_w[j + 6];
        float v0 = hin[(size_t)r0 * OUT_CH + c];
        float v1 = hin[(size_t)r1 * OUT_CH + c];
        float v2 = hin[(size_t)r2 * OUT_CH + c];
        float v3 = hin[(size_t)r3 * OUT_CH + c];
        acc = fmaf(w0, v0, acc);
        acc = fmaf(w1, v1, acc);
        acc = fmaf(w2, v2, acc);
        acc = fmaf(w3, v3, acc);
    }
    for (; j < e; j += 2) {
        int r = csr_row[j];
        acc = fmaf(csr_w[j], hin[(size_t)r * OUT_CH + c], acc);
    }
    acc += __shfl_xor(acc, 32, 64);
    if (half == 0) {
        float dv = dinv[gw];
        float agg = acc + dv * dv * hin[(size_t)gw * OUT_CH + c];
        hout[(size_t)gw * OUT_CH + c] = 0.9f * agg + 0.1f * h0[(size_t)gw * OUT_CH + c];
    }
}

// ---------------- launch ----------------

extern "C" void kernel_launch(void* const* d_in, const int* in_sizes, int n_in,
                              void* d_out, int out_size, void* d_ws, size_t ws_size,
                              hipStream_t stream) {
    const float* x  = (const float*)d_in[0];
    const int*   ei = (const int*)d_in[1];      // [2][E]
    const float* W1 = (const float*)d_in[2];
    const float* b1 = (const float*)d_in[3];
    const float* Wr = (const float*)d_in[4];
    const float* br = (const float*)d_in[5];
    const float* W2 = (const float*)d_in[6];
    const float* b2 = (const float*)d_in[7];
    float* out = (float*)d_out;

    char* ws = (char*)d_ws;
    size_t off_b = 0;
    auto take = [&](size_t bytes) {
        void* p = ws + off_b;
        off_b += (bytes + 255) & ~(size_t)255;
        return p;
    };

    // region 0: propagation-phase buffers, overlaid with xb (x in bf16).
    // xb is consumed by GEMM1 BEFORE any of these are written (stream order).
    size_t r0 = off_b;
    float* h0      = (float*)take((size_t)N_NODES * OUT_CH * 4);
    float* bufA    = (float*)take((size_t)N_NODES * OUT_CH * 4);
    float* bufB    = (float*)take((size_t)N_NODES * OUT_CH * 4);
    int*   csr_row = (int*)  take((size_t)E_EDGES * 4);
    float* csr_w   = (float*)take((size_t)E_EDGES * 4);
    float* dinv    = (float*)take((size_t)N_NODES * 4);
    int*   cnt     = (int*)  take((size_t)N_NODES * 4);
    int*   offs    = (int*)  take((size_t)(N_NODES + 1) * 4);
    int*   cursor  = (int*)  take((size_t)N_NODES * 4);
    int*   bs      = (int*)  take(1024);
    int*   bo      = (int*)  take(1024);
    size_t r0_end = off_b;
    u16* xb = (u16*)(ws + r0);                     // overlaps region 0
    size_t xb_bytes = (size_t)N_NODES * IN_CH * 2; // 102.4 MB
    size_t r0_size = r0_end - r0;
    off_b = r0 + ((xb_bytes > r0_size ? xb_bytes : r0_size) + 255 & ~(size_t)255);

    u16* h1   = (u16*)take((size_t)N_NODES * HID * 2);
    u16* xres = (u16*)take((size_t)N_NODES * HID * 2);
    u16* W1b  = (u16*)take((size_t)HID * IN_CH * 2);
    u16* Wrb  = (u16*)take((size_t)HID * HID * 2);

    const int* e_row = ei;
    const int* e_col = ei + E_EDGES;

    // 1) casts
    k_cast<<<(N_NODES * IN_CH / 4 + 255) / 256, 256, 0, stream>>>(x, xb, N_NODES * IN_CH / 4);
    k_cast<<<(HID * IN_CH / 4 + 255) / 256, 256, 0, stream>>>(W1, W1b, HID * IN_CH / 4);
    k_cast<<<(HID * HID / 4 + 255) / 256, 256, 0, stream>>>(Wr, Wrb, HID * HID / 4);

    // 2) GEMM1: h1 = relu(x @ W1^T + b1)   [consumes xb]
    dim3 g12((N_NODES + 127) / 128, HID / 128);
    gemm_mfma<IN_CH, false><<<g12, 256, 0, stream>>>(xb, W1b, b1, nullptr, h1, N_NODES);

    // 3) preprocessing (writes region 0 — xb dead after GEMM1, stream-ordered)
    hipMemsetAsync(cnt, 0, (size_t)N_NODES * 4, stream);
    hipMemsetAsync(cursor, 0, (size_t)N_NODES * 4, stream);
    const int NB = (N_NODES + 1023) / 1024;  // 98
    k_count<<<(E_EDGES + 255) / 256, 256, 0, stream>>>(e_col, cnt);
    k_dinv<<<(N_NODES + 255) / 256, 256, 0, stream>>>(cnt, dinv);
    k_blocksum<<<NB, 256, 0, stream>>>(cnt, bs);
    k_scanblocks<<<1, 128, 0, stream>>>(bs, bo, NB);
    k_scanwithin<<<NB, 256, 0, stream>>>(cnt, bo, offs);
    k_fill<<<(E_EDGES + 255) / 256, 256, 0, stream>>>(e_row, e_col, dinv, offs, cursor, csr_row, csr_w);

    // 4) GEMM2: xres = h1 + relu(h1 @ Wr^T + br)
    gemm_mfma<HID, true><<<g12, 256, 0, stream>>>(h1, Wrb, br, h1, xres, N_NODES);

    // 5) GEMM3: h0 = xres @ W2^T + b2
    gemm_out<<<(N_NODES + 127) / 128, 256, 0, stream>>>(xres, W2, b2, h0, N_NODES);

    // 6) propagation: K steps
    const float* pin = h0;
    for (int s = 0; s < K_STEPS; ++s) {
        float* pout = (s == K_STEPS - 1) ? out : ((s & 1) ? bufB : bufA);
        k_prop<<<(N_NODES * 64 + 255) / 256, 256, 0, stream>>>(pin, pout, h0, offs, csr_row, csr_w, dinv);
        pin = pout;
    }
}

// Round 3
// 1138.728 us; speedup vs baseline: 1.5903x; 1.0510x over previous
//
#include <hip/hip_runtime.h>

#define N_NODES 100000
#define E_EDGES 1600000
#define IN_CH   512
#define HID     256
#define OUT_CH  32
#define K_STEPS 10

typedef unsigned short u16;
typedef unsigned int   u32;

typedef __attribute__((ext_vector_type(8))) short bf16x8;
typedef __attribute__((ext_vector_type(4))) float f32x4;

__device__ __forceinline__ float b2f(u16 u) {
    union { u32 i; float f; } x; x.i = ((u32)u) << 16; return x.f;
}
__device__ __forceinline__ u16 f2b(float f) {
    union { float f; u32 u; } x; x.f = f;
    u32 r = x.u + 0x7fffu + ((x.u >> 16) & 1u);
    return (u16)(r >> 16);
}

// async global->LDS, 16B per lane. LDS dest is wave-uniform base + lane*16.
__device__ __forceinline__ void load_lds16(const void* g, void* l) {
    __builtin_amdgcn_global_load_lds(
        (const __attribute__((address_space(1))) unsigned int*)g,
        (__attribute__((address_space(3))) unsigned int*)l,
        16, 0, 0);
}

// ---------------- casts ----------------

__global__ __launch_bounds__(256) void k_cast(const float* __restrict__ in, u16* __restrict__ out, int n4) {
    int i = blockIdx.x * 256 + threadIdx.x;
    if (i < n4) {
        float4 f = ((const float4*)in)[i];
        ushort4 u;
        u.x = f2b(f.x); u.y = f2b(f.y); u.z = f2b(f.z); u.w = f2b(f.w);
        ((ushort4*)out)[i] = u;
    }
}

// ---------------- preprocessing: degree, dinv, scan, CSR fill ----------------

__global__ __launch_bounds__(256) void k_count(const int* __restrict__ col, int* __restrict__ cnt) {
    int i = blockIdx.x * 256 + threadIdx.x;
    if (i < E_EDGES) atomicAdd(&cnt[col[i]], 1);
}

__global__ __launch_bounds__(256) void k_dinv(const int* __restrict__ cnt, float* __restrict__ dinv) {
    int i = blockIdx.x * 256 + threadIdx.x;
    if (i < N_NODES) dinv[i] = rsqrtf((float)(cnt[i] + 1));  // +1 self-loop
}

__global__ __launch_bounds__(256) void k_blocksum(const int* __restrict__ cnt, int* __restrict__ bs) {
    int b = blockIdx.x, t = threadIdx.x;
    int idx = b * 1024 + t * 4;
    int s = 0;
    #pragma unroll
    for (int j = 0; j < 4; ++j) if (idx + j < N_NODES) s += cnt[idx + j];
    #pragma unroll
    for (int d = 32; d > 0; d >>= 1) s += __shfl_down(s, d, 64);
    __shared__ int smem[4];
    int lane = t & 63, w = t >> 6;
    if (lane == 0) smem[w] = s;
    __syncthreads();
    if (t == 0) bs[b] = smem[0] + smem[1] + smem[2] + smem[3];
}

__global__ void k_scanblocks(const int* __restrict__ bs, int* __restrict__ bo, int nb) {
    int t = threadIdx.x;  // 128 threads, nb <= 128
    int v = (t < nb) ? bs[t] : 0;
    int incl = v;
    int lane = t & 63, w = t >> 6;
    #pragma unroll
    for (int d = 1; d < 64; d <<= 1) { int tt = __shfl_up(incl, d, 64); if (lane >= d) incl += tt; }
    __shared__ int wsum[2];
    if (lane == 63) wsum[w] = incl;
    __syncthreads();
    int add = (w == 1) ? wsum[0] : 0;
    if (t < nb) bo[t] = add + incl - v;  // exclusive
}

__global__ __launch_bounds__(256) void k_scanwithin(const int* __restrict__ cnt, const int* __restrict__ bo,
                                                    int* __restrict__ off) {
    int b = blockIdx.x, t = threadIdx.x;
    int idx = b * 1024 + t * 4;
    int v[4]; int s = 0;
    #pragma unroll
    for (int j = 0; j < 4; ++j) { v[j] = (idx + j < N_NODES) ? cnt[idx + j] : 0; s += v[j]; }
    int incl = s;
    int lane = t & 63, w = t >> 6;
    #pragma unroll
    for (int d = 1; d < 64; d <<= 1) { int tt = __shfl_up(incl, d, 64); if (lane >= d) incl += tt; }
    __shared__ int wsum[4];
    if (lane == 63) wsum[w] = incl;
    __syncthreads();
    int woff = 0;
    #pragma unroll
    for (int k = 0; k < 4; ++k) if (k < w) woff += wsum[k];
    int run = bo[b] + woff + incl - s;
    #pragma unroll
    for (int j = 0; j < 4; ++j) { if (idx + j < N_NODES) off[idx + j] = run; run += v[j]; }
    if (b == 0 && t == 0) off[N_NODES] = E_EDGES;
}

// CSR fill: only the source row index (4B/edge) — weights are folded into the
// dinv-scaled propagation variable p = dinv .* h, so csr_w no longer exists.
__global__ __launch_bounds__(256) void k_fill(const int* __restrict__ row, const int* __restrict__ col,
                                              const int* __restrict__ off, int* __restrict__ cursor,
                                              int* __restrict__ csr_row) {
    int i = blockIdx.x * 256 + threadIdx.x;
    if (i < E_EDGES) {
        int c = col[i];
        int pos = off[c] + atomicAdd(&cursor[c], 1);
        csr_row[pos] = row[i];
    }
}

// ---------------- bf16 MFMA GEMM: 128x128 tile, 4 waves, 64x64/wave ----------------
// Out[m][n] = relu(A[m][:] . Bt[n][:] + bias[n]) (+ resid[m][n] if RESID), Out bf16 ld=256

template<int KDIM, bool RESID>
__global__ __launch_bounds__(256) void gemm_mfma(const u16* __restrict__ A,
                                                 const u16* __restrict__ Bt,
                                                 const float* __restrict__ bias,
                                                 const u16* __restrict__ resid,
                                                 u16* __restrict__ Out,
                                                 int M) {
    __shared__ u16 As[128 * 32];   // [row][k], 64B rows, no pad (global_load_lds layout)
    __shared__ u16 Bs[128 * 32];
    const int t = threadIdx.x;
    const int lane = t & 63, w = t >> 6;
    const int row0 = blockIdx.x * 128, col0 = blockIdx.y * 128;

    f32x4 acc[4][4] = {};

    const int rr = lane >> 2;   // row within 16-row chunk
    const int cc = lane & 3;    // 16B chunk within 64B row

    const int wr = (w >> 1) * 64, wc = (w & 1) * 64;
    const int fr = lane & 15, quad = lane >> 4;

    for (int k0 = 0; k0 < KDIM; k0 += 32) {
        #pragma unroll
        for (int rep = 0; rep < 2; ++rep) {
            int ii = w * 2 + rep;
            int gr = row0 + ii * 16 + rr;
            if (gr > M - 1) gr = M - 1;           // clamp: garbage rows never stored
            load_lds16(A + (size_t)gr * KDIM + k0 + cc * 8, &As[ii * 512]);
        }
        #pragma unroll
        for (int rep = 0; rep < 2; ++rep) {
            int ii = w * 2 + rep;
            int gc = col0 + ii * 16 + rr;         // always in-bounds (HID multiple of 128)
            load_lds16(Bt + (size_t)gc * KDIM + k0 + cc * 8, &Bs[ii * 512]);
        }
        __syncthreads();

        bf16x8 af[4], bfr[4];
        #pragma unroll
        for (int ti = 0; ti < 4; ++ti)
            af[ti] = *(const bf16x8*)&As[(wr + ti * 16 + fr) * 32 + quad * 8];
        #pragma unroll
        for (int tj = 0; tj < 4; ++tj)
            bfr[tj] = *(const bf16x8*)&Bs[(wc + tj * 16 + fr) * 32 + quad * 8];
        #pragma unroll
        for (int ti = 0; ti < 4; ++ti)
            #pragma unroll
            for (int tj = 0; tj < 4; ++tj)
                acc[ti][tj] = __builtin_amdgcn_mfma_f32_16x16x32_bf16(af[ti], bfr[tj], acc[ti][tj], 0, 0, 0);
        __syncthreads();
    }

    // epilogue: C/D layout col=lane&15, row=quad*4+reg
    #pragma unroll
    for (int tj = 0; tj < 4; ++tj) {
        int col = col0 + wc + tj * 16 + fr;
        float bv = bias[col];
        #pragma unroll
        for (int ti = 0; ti < 4; ++ti) {
            #pragma unroll
            for (int r = 0; r < 4; ++r) {
                int grow = row0 + wr + ti * 16 + quad * 4 + r;
                if (grow < M) {
                    float v = fmaxf(acc[ti][tj][r] + bv, 0.f);
                    if constexpr (RESID) v += b2f(resid[(size_t)grow * HID + col]);
                    Out[(size_t)grow * HID + col] = f2b(v);
                }
            }
        }
    }
}

// GEMM3: h0[m][c] = xres[m][:] . W2[c][:] + b2[c]  (VALU fp32, small)
// Also emits p0 = bf16(dinv[m] * h0[m][c]) — the scaled propagation variable.
__global__ __launch_bounds__(256) void gemm_out(const u16* __restrict__ xres, const float* __restrict__ W2,
                                                const float* __restrict__ b2, const float* __restrict__ dinv,
                                                float* __restrict__ h0, u16* __restrict__ p0, int M) {
    constexpr int BM = 128, BK = 16, KDIM = HID;
    __shared__ float As[BK][BM + 4];
    __shared__ float Bs[BK][OUT_CH + 4];
    int t = threadIdx.x;
    int row0 = blockIdx.x * BM;

    float acc[4][4];
    #pragma unroll
    for (int i = 0; i < 4; ++i)
        #pragma unroll
        for (int j = 0; j < 4; ++j) acc[i][j] = 0.f;

    for (int k0 = 0; k0 < KDIM; k0 += BK) {
        #pragma unroll
        for (int rep = 0; rep < 2; ++rep) {
            int idx = rep * 256 + t;
            int r = idx >> 2, ch = idx & 3;
            int gr = row0 + r;
            float v0, v1, v2, v3;
            if (gr < M) {
                ushort4 u = *(const ushort4*)&xres[(size_t)gr * KDIM + k0 + ch * 4];
                v0 = b2f(u.x); v1 = b2f(u.y); v2 = b2f(u.z); v3 = b2f(u.w);
            } else { v0 = v1 = v2 = v3 = 0.f; }
            As[ch * 4 + 0][r] = v0; As[ch * 4 + 1][r] = v1;
            As[ch * 4 + 2][r] = v2; As[ch * 4 + 3][r] = v3;
        }
        if (t < 128) {
            int nn = t >> 2, ch = t & 3;
            float4 f = *(const float4*)&W2[(size_t)nn * KDIM + k0 + ch * 4];
            Bs[ch * 4 + 0][nn] = f.x; Bs[ch * 4 + 1][nn] = f.y;
            Bs[ch * 4 + 2][nn] = f.z; Bs[ch * 4 + 3][nn] = f.w;
        }
        __syncthreads();
        int ty = t >> 3, tx = t & 7;
        #pragma unroll
        for (int kk = 0; kk < BK; ++kk) {
            float a[4], wv[4];
            *(float4*)&a[0] = *(const float4*)&As[kk][ty * 4];
            *(float4*)&wv[0] = *(const float4*)&Bs[kk][tx * 4];
            #pragma unroll
            for (int i = 0; i < 4; ++i)
                #pragma unroll
                for (int j = 0; j < 4; ++j) acc[i][j] = fmaf(a[i], wv[j], acc[i][j]);
        }
        __syncthreads();
    }
    int ty = t >> 3, tx = t & 7;
    #pragma unroll
    for (int i = 0; i < 4; ++i) {
        int gr = row0 + ty * 4 + i;
        if (gr < M) {
            float dv = dinv[gr];
            float4 v;
            v.x = acc[i][0] + b2[tx * 4 + 0];
            v.y = acc[i][1] + b2[tx * 4 + 1];
            v.z = acc[i][2] + b2[tx * 4 + 2];
            v.w = acc[i][3] + b2[tx * 4 + 3];
            *(float4*)&h0[(size_t)gr * OUT_CH + tx * 4] = v;
            ushort4 u;
            u.x = f2b(dv * v.x); u.y = f2b(dv * v.y);
            u.z = f2b(dv * v.z); u.w = f2b(dv * v.w);
            *(ushort4*)&p0[(size_t)gr * OUT_CH + tx * 4] = u;
        }
    }
}

// ---------------- propagation over p = dinv.*h, bf16 storage ----------------
// h' = 0.9*dinv[c]*(sum_{r in N(c)} p[r] + p[c]) + 0.1*h0[c];  p' = dinv[c]*h'

__global__ __launch_bounds__(256) void k_prop(const u16* __restrict__ pin, u16* __restrict__ pout,
                                              float* __restrict__ hout, const float* __restrict__ h0,
                                              const int* __restrict__ off, const int* __restrict__ csr_row,
                                              const float* __restrict__ dinv, int last) {
    int gw = (blockIdx.x * 256 + threadIdx.x) >> 6;
    if (gw >= N_NODES) return;
    int lane = threadIdx.x & 63;
    int c = lane & 31;
    int half = lane >> 5;
    int s = off[gw], e = off[gw + 1];
    float acc = 0.f;
    int j = s + half;
    // 4 edges per half in flight (8 per wave)
    for (; j + 6 < e; j += 8) {
        int r0 = csr_row[j];
        int r1 = csr_row[j + 2];
        int r2 = csr_row[j + 4];
        int r3 = csr_row[j + 6];
        float v0 = b2f(pin[(size_t)r0 * OUT_CH + c]);
        float v1 = b2f(pin[(size_t)r1 * OUT_CH + c]);
        float v2 = b2f(pin[(size_t)r2 * OUT_CH + c]);
        float v3 = b2f(pin[(size_t)r3 * OUT_CH + c]);
        acc += (v0 + v1) + (v2 + v3);
    }
    for (; j < e; j += 2) {
        acc += b2f(pin[(size_t)csr_row[j] * OUT_CH + c]);
    }
    acc += __shfl_xor(acc, 32, 64);
    if (half == 0) {
        float dv = dinv[gw];
        float self = b2f(pin[(size_t)gw * OUT_CH + c]);
        float h = 0.9f * dv * (acc + self) + 0.1f * h0[(size_t)gw * OUT_CH + c];
        if (last) hout[(size_t)gw * OUT_CH + c] = h;
        else      pout[(size_t)gw * OUT_CH + c] = f2b(dv * h);
    }
}

// ---------------- launch ----------------

extern "C" void kernel_launch(void* const* d_in, const int* in_sizes, int n_in,
                              void* d_out, int out_size, void* d_ws, size_t ws_size,
                              hipStream_t stream) {
    const float* x  = (const float*)d_in[0];
    const int*   ei = (const int*)d_in[1];      // [2][E]
    const float* W1 = (const float*)d_in[2];
    const float* b1 = (const float*)d_in[3];
    const float* Wr = (const float*)d_in[4];
    const float* br = (const float*)d_in[5];
    const float* W2 = (const float*)d_in[6];
    const float* b2 = (const float*)d_in[7];
    float* out = (float*)d_out;

    char* ws = (char*)d_ws;
    size_t off_b = 0;
    auto take = [&](size_t bytes) {
        void* p = ws + off_b;
        off_b += (bytes + 255) & ~(size_t)255;
        return p;
    };

    // region 0: propagation-phase buffers, overlaid with xb (x in bf16).
    // xb is consumed by GEMM1 BEFORE any of these are written (stream order).
    size_t r0 = off_b;
    float* h0      = (float*)take((size_t)N_NODES * OUT_CH * 4);
    u16*   pA      = (u16*)  take((size_t)N_NODES * OUT_CH * 2);
    u16*   pB      = (u16*)  take((size_t)N_NODES * OUT_CH * 2);
    int*   csr_row = (int*)  take((size_t)E_EDGES * 4);
    float* dinv    = (float*)take((size_t)N_NODES * 4);
    int*   cnt     = (int*)  take((size_t)N_NODES * 4);
    int*   offs    = (int*)  take((size_t)(N_NODES + 1) * 4);
    int*   cursor  = (int*)  take((size_t)N_NODES * 4);
    int*   bs      = (int*)  take(1024);
    int*   bo      = (int*)  take(1024);
    size_t r0_end = off_b;
    u16* xb = (u16*)(ws + r0);                     // overlaps region 0
    size_t xb_bytes = (size_t)N_NODES * IN_CH * 2; // 102.4 MB
    size_t r0_size = r0_end - r0;
    off_b = r0 + (((xb_bytes > r0_size ? xb_bytes : r0_size) + 255) & ~(size_t)255);

    u16* h1   = (u16*)take((size_t)N_NODES * HID * 2);
    u16* xres = (u16*)take((size_t)N_NODES * HID * 2);
    u16* W1b  = (u16*)take((size_t)HID * IN_CH * 2);
    u16* Wrb  = (u16*)take((size_t)HID * HID * 2);

    const int* e_row = ei;
    const int* e_col = ei + E_EDGES;

    // 1) casts
    k_cast<<<(N_NODES * IN_CH / 4 + 255) / 256, 256, 0, stream>>>(x, xb, N_NODES * IN_CH / 4);
    k_cast<<<(HID * IN_CH / 4 + 255) / 256, 256, 0, stream>>>(W1, W1b, HID * IN_CH / 4);
    k_cast<<<(HID * HID / 4 + 255) / 256, 256, 0, stream>>>(Wr, Wrb, HID * HID / 4);

    // 2) GEMM1: h1 = relu(x @ W1^T + b1)   [consumes xb]
    dim3 g12((N_NODES + 127) / 128, HID / 128);
    gemm_mfma<IN_CH, false><<<g12, 256, 0, stream>>>(xb, W1b, b1, nullptr, h1, N_NODES);

    // 3) preprocessing (writes region 0 — xb dead after GEMM1, stream-ordered)
    hipMemsetAsync(cnt, 0, (size_t)N_NODES * 4, stream);
    hipMemsetAsync(cursor, 0, (size_t)N_NODES * 4, stream);
    const int NB = (N_NODES + 1023) / 1024;  // 98
    k_count<<<(E_EDGES + 255) / 256, 256, 0, stream>>>(e_col, cnt);
    k_dinv<<<(N_NODES + 255) / 256, 256, 0, stream>>>(cnt, dinv);
    k_blocksum<<<NB, 256, 0, stream>>>(cnt, bs);
    k_scanblocks<<<1, 128, 0, stream>>>(bs, bo, NB);
    k_scanwithin<<<NB, 256, 0, stream>>>(cnt, bo, offs);
    k_fill<<<(E_EDGES + 255) / 256, 256, 0, stream>>>(e_row, e_col, offs, cursor, csr_row);

    // 4) GEMM2: xres = h1 + relu(h1 @ Wr^T + br)
    gemm_mfma<HID, true><<<g12, 256, 0, stream>>>(h1, Wrb, br, h1, xres, N_NODES);

    // 5) GEMM3: h0 = xres @ W2^T + b2 ; p0 = bf16(dinv .* h0)  -> pA
    gemm_out<<<(N_NODES + 127) / 128, 256, 0, stream>>>(xres, W2, b2, dinv, h0, pA, N_NODES);

    // 6) propagation: K steps on p (bf16), final step writes fp32 h to out
    const u16* pin = pA;
    for (int s = 0; s < K_STEPS; ++s) {
        int last = (s == K_STEPS - 1);
        u16* pout = (s & 1) ? pA : pB;
        k_prop<<<(N_NODES * 64 + 255) / 256, 256, 0, stream>>>(pin, pout, out, h0, offs, csr_row, dinv, last);
        pin = pout;
    }
}

// Round 4
// 919.739 us; speedup vs baseline: 1.9689x; 1.2381x over previous
//
#include <hip/hip_runtime.h>

#define N_NODES 100000
#define E_EDGES 1600000
#define IN_CH   512
#define HID     256
#define OUT_CH  32
#define K_STEPS 10

typedef unsigned short u16;
typedef unsigned int   u32;

typedef __attribute__((ext_vector_type(8))) short bf16x8;
typedef __attribute__((ext_vector_type(4))) float f32x4;

__device__ __forceinline__ float b2f(u16 u) {
    union { u32 i; float f; } x; x.i = ((u32)u) << 16; return x.f;
}
__device__ __forceinline__ u16 f2b(float f) {
    union { float f; u32 u; } x; x.f = f;
    u32 r = x.u + 0x7fffu + ((x.u >> 16) & 1u);
    return (u16)(r >> 16);
}

// async global->LDS, 16B per lane. LDS dest is wave-uniform base + lane*16.
__device__ __forceinline__ void load_lds16(const void* g, void* l) {
    __builtin_amdgcn_global_load_lds(
        (const __attribute__((address_space(1))) unsigned int*)g,
        (__attribute__((address_space(3))) unsigned int*)l,
        16, 0, 0);
}

// ---------------- casts (weights only; x-cast is fused into GEMM1) ----------------

__global__ __launch_bounds__(256) void k_cast(const float* __restrict__ in, u16* __restrict__ out, int n4) {
    int i = blockIdx.x * 256 + threadIdx.x;
    if (i < n4) {
        float4 f = ((const float4*)in)[i];
        ushort4 u;
        u.x = f2b(f.x); u.y = f2b(f.y); u.z = f2b(f.z); u.w = f2b(f.w);
        ((ushort4*)out)[i] = u;
    }
}

// ---------------- preprocessing: degree, dinv, scan, CSR fill ----------------

__global__ __launch_bounds__(256) void k_count(const int* __restrict__ col, int* __restrict__ cnt) {
    int i = blockIdx.x * 256 + threadIdx.x;
    if (i < E_EDGES) atomicAdd(&cnt[col[i]], 1);
}

__global__ __launch_bounds__(256) void k_dinv(const int* __restrict__ cnt, float* __restrict__ dinv) {
    int i = blockIdx.x * 256 + threadIdx.x;
    if (i < N_NODES) dinv[i] = rsqrtf((float)(cnt[i] + 1));  // +1 self-loop
}

__global__ __launch_bounds__(256) void k_blocksum(const int* __restrict__ cnt, int* __restrict__ bs) {
    int b = blockIdx.x, t = threadIdx.x;
    int idx = b * 1024 + t * 4;
    int s = 0;
    #pragma unroll
    for (int j = 0; j < 4; ++j) if (idx + j < N_NODES) s += cnt[idx + j];
    #pragma unroll
    for (int d = 32; d > 0; d >>= 1) s += __shfl_down(s, d, 64);
    __shared__ int smem[4];
    int lane = t & 63, w = t >> 6;
    if (lane == 0) smem[w] = s;
    __syncthreads();
    if (t == 0) bs[b] = smem[0] + smem[1] + smem[2] + smem[3];
}

__global__ void k_scanblocks(const int* __restrict__ bs, int* __restrict__ bo, int nb) {
    int t = threadIdx.x;  // 128 threads, nb <= 128
    int v = (t < nb) ? bs[t] : 0;
    int incl = v;
    int lane = t & 63, w = t >> 6;
    #pragma unroll
    for (int d = 1; d < 64; d <<= 1) { int tt = __shfl_up(incl, d, 64); if (lane >= d) incl += tt; }
    __shared__ int wsum[2];
    if (lane == 63) wsum[w] = incl;
    __syncthreads();
    int add = (w == 1) ? wsum[0] : 0;
    if (t < nb) bo[t] = add + incl - v;  // exclusive
}

__global__ __launch_bounds__(256) void k_scanwithin(const int* __restrict__ cnt, const int* __restrict__ bo,
                                                    int* __restrict__ off) {
    int b = blockIdx.x, t = threadIdx.x;
    int idx = b * 1024 + t * 4;
    int v[4]; int s = 0;
    #pragma unroll
    for (int j = 0; j < 4; ++j) { v[j] = (idx + j < N_NODES) ? cnt[idx + j] : 0; s += v[j]; }
    int incl = s;
    int lane = t & 63, w = t >> 6;
    #pragma unroll
    for (int d = 1; d < 64; d <<= 1) { int tt = __shfl_up(incl, d, 64); if (lane >= d) incl += tt; }
    __shared__ int wsum[4];
    if (lane == 63) wsum[w] = incl;
    __syncthreads();
    int woff = 0;
    #pragma unroll
    for (int k = 0; k < 4; ++k) if (k < w) woff += wsum[k];
    int run = bo[b] + woff + incl - s;
    #pragma unroll
    for (int j = 0; j < 4; ++j) { if (idx + j < N_NODES) off[idx + j] = run; run += v[j]; }
    if (b == 0 && t == 0) off[N_NODES] = E_EDGES;
}

// CSR fill: only source row indices (4B/edge); weights folded into p = dinv .* h.
__global__ __launch_bounds__(256) void k_fill(const int* __restrict__ row, const int* __restrict__ col,
                                              const int* __restrict__ off, int* __restrict__ cursor,
                                              int* __restrict__ csr_row) {
    int i = blockIdx.x * 256 + threadIdx.x;
    if (i < E_EDGES) {
        int c = col[i];
        int pos = off[c] + atomicAdd(&cursor[c], 1);
        csr_row[pos] = row[i];
    }
}

// ---------------- bf16 MFMA GEMM: 128x128 tile, 4 waves, 64x64/wave ----------------
// Out[m][n] = relu(A[m][:] . Bt[n][:] + bias[n]) (+ resid if RESID), Out bf16 ld=256
// AF32: A is fp32 in global; staged to LDS with in-register bf16 convert (fused cast).

template<int KDIM, bool RESID, bool AF32>
__global__ __launch_bounds__(256) void gemm_mfma(const void* __restrict__ Aptr,
                                                 const u16* __restrict__ Bt,
                                                 const float* __restrict__ bias,
                                                 const u16* __restrict__ resid,
                                                 u16* __restrict__ Out,
                                                 int M) {
    __shared__ u16 As[128 * 32];   // [row][k], 64B rows, no pad
    __shared__ u16 Bs[128 * 32];
    const int t = threadIdx.x;
    const int lane = t & 63, w = t >> 6;
    const int row0 = blockIdx.x * 128, col0 = blockIdx.y * 128;

    f32x4 acc[4][4] = {};

    const int rr = lane >> 2;   // row within 16-row chunk (global_load_lds path)
    const int cc = lane & 3;    // 16B chunk within 64B row

    const int wr = (w >> 1) * 64, wc = (w & 1) * 64;
    const int fr = lane & 15, quad = lane >> 4;

    for (int k0 = 0; k0 < KDIM; k0 += 32) {
        if constexpr (AF32) {
            const float* A = (const float*)Aptr;
            // 128 rows x 32 cols fp32 -> bf16 LDS; 1024 float4 chunks, 4/thread
            #pragma unroll
            for (int it = 0; it < 4; ++it) {
                int chunk = it * 256 + t;
                int row = chunk >> 3, seg = chunk & 7;
                int gr = row0 + row;
                if (gr > M - 1) gr = M - 1;
                float4 f = *(const float4*)&A[(size_t)gr * KDIM + k0 + seg * 4];
                u32 lo = (u32)f2b(f.x) | ((u32)f2b(f.y) << 16);
                u32 hi = (u32)f2b(f.z) | ((u32)f2b(f.w) << 16);
                *(uint2*)&As[row * 32 + seg * 4] = make_uint2(lo, hi);
            }
        } else {
            const u16* A = (const u16*)Aptr;
            #pragma unroll
            for (int rep = 0; rep < 2; ++rep) {
                int ii = w * 2 + rep;
                int gr = row0 + ii * 16 + rr;
                if (gr > M - 1) gr = M - 1;           // clamp: garbage rows never stored
                load_lds16(A + (size_t)gr * KDIM + k0 + cc * 8, &As[ii * 512]);
            }
        }
        #pragma unroll
        for (int rep = 0; rep < 2; ++rep) {
            int ii = w * 2 + rep;
            int gc = col0 + ii * 16 + rr;             // in-bounds (HID multiple of 128)
            load_lds16(Bt + (size_t)gc * KDIM + k0 + cc * 8, &Bs[ii * 512]);
        }
        __syncthreads();

        bf16x8 af[4], bfr[4];
        #pragma unroll
        for (int ti = 0; ti < 4; ++ti)
            af[ti] = *(const bf16x8*)&As[(wr + ti * 16 + fr) * 32 + quad * 8];
        #pragma unroll
        for (int tj = 0; tj < 4; ++tj)
            bfr[tj] = *(const bf16x8*)&Bs[(wc + tj * 16 + fr) * 32 + quad * 8];
        #pragma unroll
        for (int ti = 0; ti < 4; ++ti)
            #pragma unroll
            for (int tj = 0; tj < 4; ++tj)
                acc[ti][tj] = __builtin_amdgcn_mfma_f32_16x16x32_bf16(af[ti], bfr[tj], acc[ti][tj], 0, 0, 0);
        __syncthreads();
    }

    // epilogue: C/D layout col=lane&15, row=quad*4+reg
    #pragma unroll
    for (int tj = 0; tj < 4; ++tj) {
        int col = col0 + wc + tj * 16 + fr;
        float bv = bias[col];
        #pragma unroll
        for (int ti = 0; ti < 4; ++ti) {
            #pragma unroll
            for (int r = 0; r < 4; ++r) {
                int grow = row0 + wr + ti * 16 + quad * 4 + r;
                if (grow < M) {
                    float v = fmaxf(acc[ti][tj][r] + bv, 0.f);
                    if constexpr (RESID) v += b2f(resid[(size_t)grow * HID + col]);
                    Out[(size_t)grow * HID + col] = f2b(v);
                }
            }
        }
    }
}

// GEMM3: h0[m][c] = xres[m][:] . W2[c][:] + b2[c]  (VALU fp32, small)
// Also emits p0 = bf16(dinv[m] * h0[m][c]) packed 2-channels-per-u32.
__global__ __launch_bounds__(256) void gemm_out(const u16* __restrict__ xres, const float* __restrict__ W2,
                                                const float* __restrict__ b2, const float* __restrict__ dinv,
                                                float* __restrict__ h0, u16* __restrict__ p0, int M) {
    constexpr int BM = 128, BK = 16, KDIM = HID;
    __shared__ float As[BK][BM + 4];
    __shared__ float Bs[BK][OUT_CH + 4];
    int t = threadIdx.x;
    int row0 = blockIdx.x * BM;

    float acc[4][4];
    #pragma unroll
    for (int i = 0; i < 4; ++i)
        #pragma unroll
        for (int j = 0; j < 4; ++j) acc[i][j] = 0.f;

    for (int k0 = 0; k0 < KDIM; k0 += BK) {
        #pragma unroll
        for (int rep = 0; rep < 2; ++rep) {
            int idx = rep * 256 + t;
            int r = idx >> 2, ch = idx & 3;
            int gr = row0 + r;
            float v0, v1, v2, v3;
            if (gr < M) {
                ushort4 u = *(const ushort4*)&xres[(size_t)gr * KDIM + k0 + ch * 4];
                v0 = b2f(u.x); v1 = b2f(u.y); v2 = b2f(u.z); v3 = b2f(u.w);
            } else { v0 = v1 = v2 = v3 = 0.f; }
            As[ch * 4 + 0][r] = v0; As[ch * 4 + 1][r] = v1;
            As[ch * 4 + 2][r] = v2; As[ch * 4 + 3][r] = v3;
        }
        if (t < 128) {
            int nn = t >> 2, ch = t & 3;
            float4 f = *(const float4*)&W2[(size_t)nn * KDIM + k0 + ch * 4];
            Bs[ch * 4 + 0][nn] = f.x; Bs[ch * 4 + 1][nn] = f.y;
            Bs[ch * 4 + 2][nn] = f.z; Bs[ch * 4 + 3][nn] = f.w;
        }
        __syncthreads();
        int ty = t >> 3, tx = t & 7;
        #pragma unroll
        for (int kk = 0; kk < BK; ++kk) {
            float a[4], wv[4];
            *(float4*)&a[0] = *(const float4*)&As[kk][ty * 4];
            *(float4*)&wv[0] = *(const float4*)&Bs[kk][tx * 4];
            #pragma unroll
            for (int i = 0; i < 4; ++i)
                #pragma unroll
                for (int j = 0; j < 4; ++j) acc[i][j] = fmaf(a[i], wv[j], acc[i][j]);
        }
        __syncthreads();
    }
    int ty = t >> 3, tx = t & 7;
    #pragma unroll
    for (int i = 0; i < 4; ++i) {
        int gr = row0 + ty * 4 + i;
        if (gr < M) {
            float dv = dinv[gr];
            float4 v;
            v.x = acc[i][0] + b2[tx * 4 + 0];
            v.y = acc[i][1] + b2[tx * 4 + 1];
            v.z = acc[i][2] + b2[tx * 4 + 2];
            v.w = acc[i][3] + b2[tx * 4 + 3];
            *(float4*)&h0[(size_t)gr * OUT_CH + tx * 4] = v;
            ushort4 u;
            u.x = f2b(dv * v.x); u.y = f2b(dv * v.y);
            u.z = f2b(dv * v.z); u.w = f2b(dv * v.w);
            *(ushort4*)&p0[(size_t)gr * OUT_CH + tx * 4] = u;
        }
    }
}

// ---------------- propagation: 16 lanes/node, 2 bf16 channels/lane ----------------
// h' = 0.9*dinv[c]*(sum_{r in N(c)} p[r] + p[c]) + 0.1*h0[c];  p' = dinv[c]*h'
// p layout: u32[node][16], element l = channels (2l | 2l+1<<16)

__global__ __launch_bounds__(256) void k_prop(const u32* __restrict__ pin, u32* __restrict__ pout,
                                              float* __restrict__ hout, const float* __restrict__ h0,
                                              const int* __restrict__ off, const int* __restrict__ csr_row,
                                              const float* __restrict__ dinv, int last) {
    int t = threadIdx.x;
    int gw = blockIdx.x * 16 + (t >> 4);     // node (grid = N/16 blocks, N%16==0)
    int l = t & 15;                          // lane within group = channel pair
    int lbase = t & 48;                      // group base lane within wave
    int s = off[gw], e = off[gw + 1];
    float dv = dinv[gw];
    u32 selfp = pin[(size_t)gw * 16 + l];
    float2 h0v = ((const float2*)h0)[(size_t)gw * 16 + l];

    float acc0 = 0.f, acc1 = 0.f;
    for (int base = s; base < e; base += 16) {
        int n = e - base; if (n > 16) n = 16;
        int idx = (base + l < e) ? csr_row[base + l] : 0;   // 16x4B coalesced
        int i = 0;
        for (; i + 3 < n; i += 4) {
            int r0 = __shfl(idx, lbase + i + 0, 64);
            int r1 = __shfl(idx, lbase + i + 1, 64);
            int r2 = __shfl(idx, lbase + i + 2, 64);
            int r3 = __shfl(idx, lbase + i + 3, 64);
            u32 v0 = pin[(size_t)r0 * 16 + l];
            u32 v1 = pin[(size_t)r1 * 16 + l];
            u32 v2 = pin[(size_t)r2 * 16 + l];
            u32 v3 = pin[(size_t)r3 * 16 + l];
            acc0 += (b2f((u16)v0) + b2f((u16)v1)) + (b2f((u16)v2) + b2f((u16)v3));
            acc1 += (b2f((u16)(v0 >> 16)) + b2f((u16)(v1 >> 16))) +
                    (b2f((u16)(v2 >> 16)) + b2f((u16)(v3 >> 16)));
        }
        for (; i < n; ++i) {
            int r = __shfl(idx, lbase + i, 64);
            u32 v = pin[(size_t)r * 16 + l];
            acc0 += b2f((u16)v);
            acc1 += b2f((u16)(v >> 16));
        }
    }
    acc0 += b2f((u16)selfp);
    acc1 += b2f((u16)(selfp >> 16));
    float hc0 = 0.9f * dv * acc0 + 0.1f * h0v.x;
    float hc1 = 0.9f * dv * acc1 + 0.1f * h0v.y;
    if (last) {
        ((float2*)hout)[(size_t)gw * 16 + l] = make_float2(hc0, hc1);
    } else {
        pout[(size_t)gw * 16 + l] = (u32)f2b(dv * hc0) | ((u32)f2b(dv * hc1) << 16);
    }
}

// ---------------- launch ----------------

extern "C" void kernel_launch(void* const* d_in, const int* in_sizes, int n_in,
                              void* d_out, int out_size, void* d_ws, size_t ws_size,
                              hipStream_t stream) {
    const float* x  = (const float*)d_in[0];
    const int*   ei = (const int*)d_in[1];      // [2][E]
    const float* W1 = (const float*)d_in[2];
    const float* b1 = (const float*)d_in[3];
    const float* Wr = (const float*)d_in[4];
    const float* br = (const float*)d_in[5];
    const float* W2 = (const float*)d_in[6];
    const float* b2 = (const float*)d_in[7];
    float* out = (float*)d_out;

    char* ws = (char*)d_ws;
    size_t off_b = 0;
    auto take = [&](size_t bytes) {
        void* p = ws + off_b;
        off_b += (bytes + 255) & ~(size_t)255;
        return p;
    };

    float* h0      = (float*)take((size_t)N_NODES * OUT_CH * 4);
    u16*   pA      = (u16*)  take((size_t)N_NODES * OUT_CH * 2);
    u16*   pB      = (u16*)  take((size_t)N_NODES * OUT_CH * 2);
    int*   csr_row = (int*)  take((size_t)E_EDGES * 4);
    float* dinv    = (float*)take((size_t)N_NODES * 4);
    int*   cnt     = (int*)  take((size_t)N_NODES * 4);
    int*   offs    = (int*)  take((size_t)(N_NODES + 1) * 4);
    int*   cursor  = (int*)  take((size_t)N_NODES * 4);
    int*   bs      = (int*)  take(1024);
    int*   bo      = (int*)  take(1024);
    u16*   h1      = (u16*)  take((size_t)N_NODES * HID * 2);
    u16*   xres    = (u16*)  take((size_t)N_NODES * HID * 2);
    u16*   W1b     = (u16*)  take((size_t)HID * IN_CH * 2);
    u16*   Wrb     = (u16*)  take((size_t)HID * HID * 2);

    const int* e_row = ei;
    const int* e_col = ei + E_EDGES;

    // 1) weight casts (x cast is fused into GEMM1)
    k_cast<<<(HID * IN_CH / 4 + 255) / 256, 256, 0, stream>>>(W1, W1b, HID * IN_CH / 4);
    k_cast<<<(HID * HID / 4 + 255) / 256, 256, 0, stream>>>(Wr, Wrb, HID * HID / 4);

    // 2) GEMM1: h1 = relu(x @ W1^T + b1), fp32 A staged with in-register cast
    dim3 g12((N_NODES + 127) / 128, HID / 128);
    gemm_mfma<IN_CH, false, true><<<g12, 256, 0, stream>>>(x, W1b, b1, nullptr, h1, N_NODES);

    // 3) preprocessing
    hipMemsetAsync(cnt, 0, (size_t)N_NODES * 4, stream);
    hipMemsetAsync(cursor, 0, (size_t)N_NODES * 4, stream);
    const int NB = (N_NODES + 1023) / 1024;  // 98
    k_count<<<(E_EDGES + 255) / 256, 256, 0, stream>>>(e_col, cnt);
    k_dinv<<<(N_NODES + 255) / 256, 256, 0, stream>>>(cnt, dinv);
    k_blocksum<<<NB, 256, 0, stream>>>(cnt, bs);
    k_scanblocks<<<1, 128, 0, stream>>>(bs, bo, NB);
    k_scanwithin<<<NB, 256, 0, stream>>>(cnt, bo, offs);
    k_fill<<<(E_EDGES + 255) / 256, 256, 0, stream>>>(e_row, e_col, offs, cursor, csr_row);

    // 4) GEMM2: xres = h1 + relu(h1 @ Wr^T + br)
    gemm_mfma<HID, true, false><<<g12, 256, 0, stream>>>(h1, Wrb, br, h1, xres, N_NODES);

    // 5) GEMM3: h0 = xres @ W2^T + b2 ; p0 = bf16(dinv .* h0) -> pA
    gemm_out<<<(N_NODES + 127) / 128, 256, 0, stream>>>(xres, W2, b2, dinv, h0, pA, N_NODES);

    // 6) propagation: K steps on packed bf16 p, final step writes fp32 h to out
    const u32* pin = (const u32*)pA;
    for (int s = 0; s < K_STEPS; ++s) {
        int last = (s == K_STEPS - 1);
        u32* pout = (u32*)((s & 1) ? pA : pB);
        k_prop<<<N_NODES / 16, 256, 0, stream>>>(pin, pout, out, h0, offs, csr_row, dinv, last);
        pin = pout;
    }
}

// Round 5
// 888.981 us; speedup vs baseline: 2.0370x; 1.0346x over previous
//
#include <hip/hip_runtime.h>

#define N_NODES 100000
#define E_EDGES 1600000
#define IN_CH   512
#define HID     256
#define OUT_CH  32
#define K_STEPS 10
#define EPAD    (E_EDGES + 16 * N_NODES)   // worst-case padded CSR length

typedef unsigned short u16;
typedef unsigned int   u32;

typedef __attribute__((ext_vector_type(8))) short bf16x8;
typedef __attribute__((ext_vector_type(4))) float f32x4;

__device__ __forceinline__ float b2f(u16 u) {
    union { u32 i; float f; } x; x.i = ((u32)u) << 16; return x.f;
}
__device__ __forceinline__ u16 f2b(float f) {
    union { float f; u32 u; } x; x.f = f;
    u32 r = x.u + 0x7fffu + ((x.u >> 16) & 1u);
    return (u16)(r >> 16);
}

// async global->LDS, 16B per lane. LDS dest is wave-uniform base + lane*16.
__device__ __forceinline__ void load_lds16(const void* g, void* l) {
    __builtin_amdgcn_global_load_lds(
        (const __attribute__((address_space(1))) unsigned int*)g,
        (__attribute__((address_space(3))) unsigned int*)l,
        16, 0, 0);
}

// ---------------- casts (weights only) ----------------

__global__ __launch_bounds__(256) void k_cast(const float* __restrict__ in, u16* __restrict__ out, int n4) {
    int i = blockIdx.x * 256 + threadIdx.x;
    if (i < n4) {
        float4 f = ((const float4*)in)[i];
        ushort4 u;
        u.x = f2b(f.x); u.y = f2b(f.y); u.z = f2b(f.z); u.w = f2b(f.w);
        ((ushort4*)out)[i] = u;
    }
}

// ---------------- preprocessing: degree, dinv, padded scan, CSR fill ----------------

__global__ __launch_bounds__(256) void k_count(const int* __restrict__ col, int* __restrict__ cnt) {
    int i = blockIdx.x * 256 + threadIdx.x;
    if (i < E_EDGES) atomicAdd(&cnt[col[i]], 1);
}

__global__ __launch_bounds__(256) void k_dinv(const int* __restrict__ cnt, float* __restrict__ dinv) {
    int i = blockIdx.x * 256 + threadIdx.x;
    if (i < N_NODES) dinv[i] = rsqrtf((float)(cnt[i] + 1));  // +1 self-loop
}

__device__ __forceinline__ int pad16(int v) { return (v + 15) & ~15; }

__global__ __launch_bounds__(256) void k_blocksum(const int* __restrict__ cnt, int* __restrict__ bs) {
    int b = blockIdx.x, t = threadIdx.x;
    int idx = b * 1024 + t * 4;
    int s = 0;
    #pragma unroll
    for (int j = 0; j < 4; ++j) if (idx + j < N_NODES) s += pad16(cnt[idx + j]);
    #pragma unroll
    for (int d = 32; d > 0; d >>= 1) s += __shfl_down(s, d, 64);
    __shared__ int smem[4];
    int lane = t & 63, w = t >> 6;
    if (lane == 0) smem[w] = s;
    __syncthreads();
    if (t == 0) bs[b] = smem[0] + smem[1] + smem[2] + smem[3];
}

__global__ void k_scanblocks(const int* __restrict__ bs, int* __restrict__ bo, int nb) {
    int t = threadIdx.x;  // 128 threads, nb <= 128
    int v = (t < nb) ? bs[t] : 0;
    int incl = v;
    int lane = t & 63, w = t >> 6;
    #pragma unroll
    for (int d = 1; d < 64; d <<= 1) { int tt = __shfl_up(incl, d, 64); if (lane >= d) incl += tt; }
    __shared__ int wsum[2];
    if (lane == 63) wsum[w] = incl;
    __syncthreads();
    int add = (w == 1) ? wsum[0] : 0;
    if (t < nb) bo[t] = add + incl - v;  // exclusive
}

__global__ __launch_bounds__(256) void k_scanwithin(const int* __restrict__ cnt, const int* __restrict__ bo,
                                                    int* __restrict__ off) {
    int b = blockIdx.x, t = threadIdx.x;
    int idx = b * 1024 + t * 4;
    int v[4]; int s = 0;
    #pragma unroll
    for (int j = 0; j < 4; ++j) { v[j] = (idx + j < N_NODES) ? pad16(cnt[idx + j]) : 0; s += v[j]; }
    int incl = s;
    int lane = t & 63, w = t >> 6;
    #pragma unroll
    for (int d = 1; d < 64; d <<= 1) { int tt = __shfl_up(incl, d, 64); if (lane >= d) incl += tt; }
    __shared__ int wsum[4];
    if (lane == 63) wsum[w] = incl;
    __syncthreads();
    int woff = 0;
    #pragma unroll
    for (int k = 0; k < 4; ++k) if (k < w) woff += wsum[k];
    int run = bo[b] + woff + incl - s;
    #pragma unroll
    for (int j = 0; j < 4; ++j) { if (idx + j < N_NODES) off[idx + j] = run; run += v[j]; }
}

__global__ __launch_bounds__(256) void k_total(const int* __restrict__ bo, const int* __restrict__ bs,
                                               int* __restrict__ off, int nb) {
    off[N_NODES] = bo[nb - 1] + bs[nb - 1];
}

// prefill padded CSR with the dummy node index (p[N] == 0 always)
__global__ __launch_bounds__(256) void k_filldummy(int* __restrict__ csr_row) {
    int i = blockIdx.x * 256 + threadIdx.x;
    if (i < EPAD) csr_row[i] = N_NODES;
}

__global__ __launch_bounds__(256) void k_fill(const int* __restrict__ row, const int* __restrict__ col,
                                              const int* __restrict__ off, int* __restrict__ cursor,
                                              int* __restrict__ csr_row) {
    int i = blockIdx.x * 256 + threadIdx.x;
    if (i < E_EDGES) {
        int c = col[i];
        int pos = off[c] + atomicAdd(&cursor[c], 1);
        csr_row[pos] = row[i];
    }
}

// ---------------- GEMM1: fp32 A fused-cast, LDS double-buffer, 1 barrier/iter ----------------
// h1[m][n] = relu(x[m][:] . W1b[n][:] + b1[n]), 128x128 tile, 4 waves, 64x64/wave

__global__ __launch_bounds__(256) void gemm1_mfma(const float* __restrict__ A,
                                                  const u16* __restrict__ Bt,
                                                  const float* __restrict__ bias,
                                                  u16* __restrict__ Out, int M) {
    __shared__ u16 As[2][128 * 32];
    __shared__ u16 Bs[2][128 * 32];
    const int t = threadIdx.x;
    const int lane = t & 63, w = t >> 6;
    const int row0 = blockIdx.x * 128, col0 = blockIdx.y * 128;
    const int rr = lane >> 2, cc = lane & 3;
    const int wr = (w >> 1) * 64, wc = (w & 1) * 64;
    const int fr = lane & 15, quad = lane >> 4;

    f32x4 acc[4][4] = {};
    float4 fp[4];
    int arow[4], aseg[4];
    #pragma unroll
    for (int it = 0; it < 4; ++it) {
        int chunk = it * 256 + t;
        arow[it] = chunk >> 3; aseg[it] = chunk & 7;
    }

    auto prefA = [&](int k0) {
        #pragma unroll
        for (int it = 0; it < 4; ++it) {
            int gr = row0 + arow[it]; if (gr > M - 1) gr = M - 1;
            fp[it] = *(const float4*)&A[(size_t)gr * IN_CH + k0 + aseg[it] * 4];
        }
    };
    auto writeA = [&](int b) {
        #pragma unroll
        for (int it = 0; it < 4; ++it) {
            u32 lo = (u32)f2b(fp[it].x) | ((u32)f2b(fp[it].y) << 16);
            u32 hi = (u32)f2b(fp[it].z) | ((u32)f2b(fp[it].w) << 16);
            *(uint2*)&As[b][arow[it] * 32 + aseg[it] * 4] = make_uint2(lo, hi);
        }
    };
    auto loadB = [&](int k0, int b) {
        #pragma unroll
        for (int rep = 0; rep < 2; ++rep) {
            int ii = w * 2 + rep;
            int gc = col0 + ii * 16 + rr;
            load_lds16(Bt + (size_t)gc * IN_CH + k0 + cc * 8, &Bs[b][ii * 512]);
        }
    };

    prefA(0);
    loadB(0, 0);
    writeA(0);
    __syncthreads();

    for (int it = 0; it < IN_CH / 32; ++it) {
        const int cur = it & 1;
        const bool more = (it < IN_CH / 32 - 1);
        if (more) prefA((it + 1) * 32);          // next A tile: global->reg, in flight
        bf16x8 af[4], bfr[4];
        #pragma unroll
        for (int ti = 0; ti < 4; ++ti)
            af[ti] = *(const bf16x8*)&As[cur][(wr + ti * 16 + fr) * 32 + quad * 8];
        #pragma unroll
        for (int tj = 0; tj < 4; ++tj)
            bfr[tj] = *(const bf16x8*)&Bs[cur][(wc + tj * 16 + fr) * 32 + quad * 8];
        #pragma unroll
        for (int ti = 0; ti < 4; ++ti)
            #pragma unroll
            for (int tj = 0; tj < 4; ++tj)
                acc[ti][tj] = __builtin_amdgcn_mfma_f32_16x16x32_bf16(af[ti], bfr[tj], acc[ti][tj], 0, 0, 0);
        if (more) {
            loadB((it + 1) * 32, cur ^ 1);       // async B early
            writeA(cur ^ 1);                     // convert + ds_write
            __syncthreads();                     // single barrier per iter
        }
    }

    #pragma unroll
    for (int tj = 0; tj < 4; ++tj) {
        int col = col0 + wc + tj * 16 + fr;
        float bv = bias[col];
        #pragma unroll
        for (int ti = 0; ti < 4; ++ti) {
            #pragma unroll
            for (int r = 0; r < 4; ++r) {
                int grow = row0 + wr + ti * 16 + quad * 4 + r;
                if (grow < M) {
                    float v = fmaxf(acc[ti][tj][r] + bv, 0.f);
                    Out[(size_t)grow * HID + col] = f2b(v);
                }
            }
        }
    }
}

// ---------------- GEMM2: bf16 A via global_load_lds (m97 structure) ----------------

template<int KDIM, bool RESID>
__global__ __launch_bounds__(256) void gemm_mfma(const u16* __restrict__ A,
                                                 const u16* __restrict__ Bt,
                                                 const float* __restrict__ bias,
                                                 const u16* __restrict__ resid,
                                                 u16* __restrict__ Out,
                                                 int M) {
    __shared__ u16 As[128 * 32];
    __shared__ u16 Bs[128 * 32];
    const int t = threadIdx.x;
    const int lane = t & 63, w = t >> 6;
    const int row0 = blockIdx.x * 128, col0 = blockIdx.y * 128;

    f32x4 acc[4][4] = {};
    const int rr = lane >> 2, cc = lane & 3;
    const int wr = (w >> 1) * 64, wc = (w & 1) * 64;
    const int fr = lane & 15, quad = lane >> 4;

    for (int k0 = 0; k0 < KDIM; k0 += 32) {
        #pragma unroll
        for (int rep = 0; rep < 2; ++rep) {
            int ii = w * 2 + rep;
            int gr = row0 + ii * 16 + rr;
            if (gr > M - 1) gr = M - 1;
            load_lds16(A + (size_t)gr * KDIM + k0 + cc * 8, &As[ii * 512]);
        }
        #pragma unroll
        for (int rep = 0; rep < 2; ++rep) {
            int ii = w * 2 + rep;
            int gc = col0 + ii * 16 + rr;
            load_lds16(Bt + (size_t)gc * KDIM + k0 + cc * 8, &Bs[ii * 512]);
        }
        __syncthreads();

        bf16x8 af[4], bfr[4];
        #pragma unroll
        for (int ti = 0; ti < 4; ++ti)
            af[ti] = *(const bf16x8*)&As[(wr + ti * 16 + fr) * 32 + quad * 8];
        #pragma unroll
        for (int tj = 0; tj < 4; ++tj)
            bfr[tj] = *(const bf16x8*)&Bs[(wc + tj * 16 + fr) * 32 + quad * 8];
        #pragma unroll
        for (int ti = 0; ti < 4; ++ti)
            #pragma unroll
            for (int tj = 0; tj < 4; ++tj)
                acc[ti][tj] = __builtin_amdgcn_mfma_f32_16x16x32_bf16(af[ti], bfr[tj], acc[ti][tj], 0, 0, 0);
        __syncthreads();
    }

    #pragma unroll
    for (int tj = 0; tj < 4; ++tj) {
        int col = col0 + wc + tj * 16 + fr;
        float bv = bias[col];
        #pragma unroll
        for (int ti = 0; ti < 4; ++ti) {
            #pragma unroll
            for (int r = 0; r < 4; ++r) {
                int grow = row0 + wr + ti * 16 + quad * 4 + r;
                if (grow < M) {
                    float v = fmaxf(acc[ti][tj][r] + bv, 0.f);
                    if constexpr (RESID) v += b2f(resid[(size_t)grow * HID + col]);
                    Out[(size_t)grow * HID + col] = f2b(v);
                }
            }
        }
    }
}

// GEMM3: h0[m][c] = xres[m][:] . W2[c][:] + b2[c]; also p0 = bf16(dinv .* h0)
__global__ __launch_bounds__(256) void gemm_out(const u16* __restrict__ xres, const float* __restrict__ W2,
                                                const float* __restrict__ b2, const float* __restrict__ dinv,
                                                float* __restrict__ h0, u16* __restrict__ p0, int M) {
    constexpr int BM = 128, BK = 16, KDIM = HID;
    __shared__ float As[BK][BM + 4];
    __shared__ float Bs[BK][OUT_CH + 4];
    int t = threadIdx.x;
    int row0 = blockIdx.x * BM;

    float acc[4][4];
    #pragma unroll
    for (int i = 0; i < 4; ++i)
        #pragma unroll
        for (int j = 0; j < 4; ++j) acc[i][j] = 0.f;

    for (int k0 = 0; k0 < KDIM; k0 += BK) {
        #pragma unroll
        for (int rep = 0; rep < 2; ++rep) {
            int idx = rep * 256 + t;
            int r = idx >> 2, ch = idx & 3;
            int gr = row0 + r;
            float v0, v1, v2, v3;
            if (gr < M) {
                ushort4 u = *(const ushort4*)&xres[(size_t)gr * KDIM + k0 + ch * 4];
                v0 = b2f(u.x); v1 = b2f(u.y); v2 = b2f(u.z); v3 = b2f(u.w);
            } else { v0 = v1 = v2 = v3 = 0.f; }
            As[ch * 4 + 0][r] = v0; As[ch * 4 + 1][r] = v1;
            As[ch * 4 + 2][r] = v2; As[ch * 4 + 3][r] = v3;
        }
        if (t < 128) {
            int nn = t >> 2, ch = t & 3;
            float4 f = *(const float4*)&W2[(size_t)nn * KDIM + k0 + ch * 4];
            Bs[ch * 4 + 0][nn] = f.x; Bs[ch * 4 + 1][nn] = f.y;
            Bs[ch * 4 + 2][nn] = f.z; Bs[ch * 4 + 3][nn] = f.w;
        }
        __syncthreads();
        int ty = t >> 3, tx = t & 7;
        #pragma unroll
        for (int kk = 0; kk < BK; ++kk) {
            float a[4], wv[4];
            *(float4*)&a[0] = *(const float4*)&As[kk][ty * 4];
            *(float4*)&wv[0] = *(const float4*)&Bs[kk][tx * 4];
            #pragma unroll
            for (int i = 0; i < 4; ++i)
                #pragma unroll
                for (int j = 0; j < 4; ++j) acc[i][j] = fmaf(a[i], wv[j], acc[i][j]);
        }
        __syncthreads();
    }
    int ty = t >> 3, tx = t & 7;
    #pragma unroll
    for (int i = 0; i < 4; ++i) {
        int gr = row0 + ty * 4 + i;
        if (gr < M) {
            float dv = dinv[gr];
            float4 v;
            v.x = acc[i][0] + b2[tx * 4 + 0];
            v.y = acc[i][1] + b2[tx * 4 + 1];
            v.z = acc[i][2] + b2[tx * 4 + 2];
            v.w = acc[i][3] + b2[tx * 4 + 3];
            *(float4*)&h0[(size_t)gr * OUT_CH + tx * 4] = v;
            ushort4 u;
            u.x = f2b(dv * v.x); u.y = f2b(dv * v.y);
            u.z = f2b(dv * v.z); u.w = f2b(dv * v.w);
            *(ushort4*)&p0[(size_t)gr * OUT_CH + tx * 4] = u;
        }
    }
}

// ---------------- propagation: 16 lanes/node, padded CSR, 16 gathers in flight ----------------
// p layout: u32[node][16], element l = channels (2l | 2l+1<<16); row N_NODES is all-zero.

__global__ __launch_bounds__(256) void k_prop(const u32* __restrict__ pin, u32* __restrict__ pout,
                                              float* __restrict__ hout, const float* __restrict__ h0,
                                              const int* __restrict__ off, const int* __restrict__ csr_row,
                                              const float* __restrict__ dinv, int last) {
    int t = threadIdx.x;
    int gw = blockIdx.x * 16 + (t >> 4);     // node (grid = N/16 blocks, N%16==0)
    int l = t & 15;
    int lbase = t & 48;
    int s = off[gw], e = off[gw + 1];        // (e-s) % 16 == 0 by construction
    float dv = dinv[gw];
    u32 selfp = pin[(size_t)gw * 16 + l];
    float2 h0v = ((const float2*)h0)[(size_t)gw * 16 + l];

    float acc0 = 0.f, acc1 = 0.f;
    for (int base = s; base < e; base += 16) {
        int idx = csr_row[base + l];          // 16x4B coalesced per group
        u32 v[16];
        #pragma unroll
        for (int i = 0; i < 16; ++i) {
            int r = __shfl(idx, lbase + i, 64);
            v[i] = pin[(size_t)r * 16 + l];   // 16 independent gathers in flight
        }
        #pragma unroll
        for (int i = 0; i < 16; ++i) {
            union { u32 u; float f; } a, b;
            a.u = v[i] << 16; b.u = v[i] & 0xffff0000u;
            acc0 += a.f; acc1 += b.f;
        }
    }
    acc0 += b2f((u16)selfp);
    acc1 += b2f((u16)(selfp >> 16));
    float hc0 = 0.9f * dv * acc0 + 0.1f * h0v.x;
    float hc1 = 0.9f * dv * acc1 + 0.1f * h0v.y;
    if (last) {
        ((float2*)hout)[(size_t)gw * 16 + l] = make_float2(hc0, hc1);
    } else {
        pout[(size_t)gw * 16 + l] = (u32)f2b(dv * hc0) | ((u32)f2b(dv * hc1) << 16);
    }
}

// ---------------- launch ----------------

extern "C" void kernel_launch(void* const* d_in, const int* in_sizes, int n_in,
                              void* d_out, int out_size, void* d_ws, size_t ws_size,
                              hipStream_t stream) {
    const float* x  = (const float*)d_in[0];
    const int*   ei = (const int*)d_in[1];      // [2][E]
    const float* W1 = (const float*)d_in[2];
    const float* b1 = (const float*)d_in[3];
    const float* Wr = (const float*)d_in[4];
    const float* br = (const float*)d_in[5];
    const float* W2 = (const float*)d_in[6];
    const float* b2 = (const float*)d_in[7];
    float* out = (float*)d_out;

    char* ws = (char*)d_ws;
    size_t off_b = 0;
    auto take = [&](size_t bytes) {
        void* p = ws + off_b;
        off_b += (bytes + 255) & ~(size_t)255;
        return p;
    };

    float* h0      = (float*)take((size_t)N_NODES * OUT_CH * 4);
    u16*   pA      = (u16*)  take((size_t)(N_NODES + 1) * OUT_CH * 2);
    u16*   pB      = (u16*)  take((size_t)(N_NODES + 1) * OUT_CH * 2);
    int*   csr_row = (int*)  take((size_t)EPAD * 4);
    float* dinv    = (float*)take((size_t)N_NODES * 4);
    int*   cnt     = (int*)  take((size_t)N_NODES * 4);
    int*   offs    = (int*)  take((size_t)(N_NODES + 1) * 4);
    int*   cursor  = (int*)  take((size_t)N_NODES * 4);
    int*   bs      = (int*)  take(1024);
    int*   bo      = (int*)  take(1024);
    u16*   h1      = (u16*)  take((size_t)N_NODES * HID * 2);
    u16*   xres    = (u16*)  take((size_t)N_NODES * HID * 2);
    u16*   W1b     = (u16*)  take((size_t)HID * IN_CH * 2);
    u16*   Wrb     = (u16*)  take((size_t)HID * HID * 2);

    const int* e_row = ei;
    const int* e_col = ei + E_EDGES;

    // 1) weight casts
    k_cast<<<(HID * IN_CH / 4 + 255) / 256, 256, 0, stream>>>(W1, W1b, HID * IN_CH / 4);
    k_cast<<<(HID * HID / 4 + 255) / 256, 256, 0, stream>>>(Wr, Wrb, HID * HID / 4);

    // 2) GEMM1: h1 = relu(x @ W1^T + b1), pipelined fused-cast
    dim3 g12((N_NODES + 127) / 128, HID / 128);
    gemm1_mfma<<<g12, 256, 0, stream>>>(x, W1b, b1, h1, N_NODES);

    // 3) preprocessing (padded CSR)
    hipMemsetAsync(cnt, 0, (size_t)N_NODES * 4, stream);
    hipMemsetAsync(cursor, 0, (size_t)N_NODES * 4, stream);
    hipMemsetAsync(pA + (size_t)N_NODES * OUT_CH, 0, OUT_CH * 2, stream);  // zero dummy row
    hipMemsetAsync(pB + (size_t)N_NODES * OUT_CH, 0, OUT_CH * 2, stream);
    const int NB = (N_NODES + 1023) / 1024;  // 98
    k_count<<<(E_EDGES + 255) / 256, 256, 0, stream>>>(e_col, cnt);
    k_dinv<<<(N_NODES + 255) / 256, 256, 0, stream>>>(cnt, dinv);
    k_blocksum<<<NB, 256, 0, stream>>>(cnt, bs);
    k_scanblocks<<<1, 128, 0, stream>>>(bs, bo, NB);
    k_scanwithin<<<NB, 256, 0, stream>>>(cnt, bo, offs);
    k_total<<<1, 1, 0, stream>>>(bo, bs, offs, NB);
    k_filldummy<<<(EPAD + 255) / 256, 256, 0, stream>>>(csr_row);
    k_fill<<<(E_EDGES + 255) / 256, 256, 0, stream>>>(e_row, e_col, offs, cursor, csr_row);

    // 4) GEMM2: xres = h1 + relu(h1 @ Wr^T + br)
    gemm_mfma<HID, true><<<g12, 256, 0, stream>>>(h1, Wrb, br, h1, xres, N_NODES);

    // 5) GEMM3: h0 = xres @ W2^T + b2 ; p0 = bf16(dinv .* h0) -> pA
    gemm_out<<<(N_NODES + 127) / 128, 256, 0, stream>>>(xres, W2, b2, dinv, h0, pA, N_NODES);

    // 6) propagation: K steps on packed bf16 p, final step writes fp32 h to out
    const u32* pin = (const u32*)pA;
    for (int s = 0; s < K_STEPS; ++s) {
        int last = (s == K_STEPS - 1);
        u32* pout = (u32*)((s & 1) ? pA : pB);
        k_prop<<<N_NODES / 16, 256, 0, stream>>>(pin, pout, out, h0, offs, csr_row, dinv, last);
        pin = pout;
    }
}